// Round 8
// baseline (258.163 us; speedup 1.0000x reference)
//
#include <hip/hip_runtime.h>
#include <math.h>

#define NC 722
#define NROWS 65536
#define PAIRS_PER_WAVE 4
#define ROWS_PER_WAVE 8              // 4 aligned row-pairs
#define WAVES_PER_BLOCK 4
#define ROWS_PER_BLOCK 32
#define NF4 361                      // float4 per row-pair (1444 floats)
#define KITERS 6                     // ceil(361/64)
#define NBLOCKS (NROWS / ROWS_PER_BLOCK)   // 2048

__global__ __launch_bounds__(256) void ce_gauss_kernel(
        const float* __restrict__ pred,
        const int* __restrict__ target,
        float* __restrict__ partials) {
    const int lane = threadIdx.x & 63;
    const int wave = threadIdx.x >> 6;
    __shared__ float wave_sums[WAVES_PER_BLOCK];

    const int row0 = blockIdx.x * ROWS_PER_BLOCK + wave * ROWS_PER_WAVE;

    // ---- phase 1: issue ALL 24 float4 loads unconditionally ----
    // Pair p = rows (row0+2p, row0+2p+1): 1444 floats = exactly 361 float4,
    // 16B-aligned since row0+2p is even and 722*even % 4 == 0.
    const float4* __restrict__ p4[PAIRS_PER_WAVE];
    #pragma unroll
    for (int p = 0; p < PAIRS_PER_WAVE; ++p)
        p4[p] = (const float4*)(pred + (size_t)(row0 + 2 * p) * NC);

    float4 v[PAIRS_PER_WAVE][KITERS];
    #pragma unroll
    for (int k = 0; k < KITERS; ++k) {
        int g = lane + (k << 6);
        if (g > NF4 - 1) g = NF4 - 1;       // clamp; only k=5, lane>40
        #pragma unroll
        for (int p = 0; p < PAIRS_PER_WAVE; ++p)
            v[p][k] = p4[p][g];
    }

    // targets: wave-uniform scalar loads (no arrays w/ dynamic index)
    const int t0 = target[row0 + 0], t1 = target[row0 + 1];
    const int t2 = target[row0 + 2], t3 = target[row0 + 3];
    const int t4 = target[row0 + 4], t5 = target[row0 + 5];
    const int t6 = target[row0 + 6], t7 = target[row0 + 7];

    // ---- phase 2: exp + accumulate ----
    // k=0,1: pure rowA.  k=3,4: pure rowB.  k=5: pure rowB, lane<41 valid.
    // k=2 (g in [128,192)): boundary at g==180 (x,y->A elems 720,721; z,w->B 0,1).
    float se[ROWS_PER_WAVE] = {0.f,0.f,0.f,0.f,0.f,0.f,0.f,0.f};
    #pragma unroll
    for (int p = 0; p < PAIRS_PER_WAVE; ++p) {
        float sa = 0.f, sb = 0.f;
        #pragma unroll
        for (int k = 0; k < KITERS; ++k) {
            const float4 q = v[p][k];
            const float e0 = __expf(q.x), e1 = __expf(q.y);
            const float e2 = __expf(q.z), e3 = __expf(q.w);
            const float sxy = e0 + e1, szw = e2 + e3, s4 = sxy + szw;
            if (k <= 1) {
                sa += s4;
            } else if (k >= 3) {
                const bool valid = (k < 5) || (lane < 41);
                sb += valid ? s4 : 0.f;
            } else {  // k == 2, g = 128 + lane
                const int g = 128 + lane;
                sa += (g < 180) ? s4 : ((g == 180) ? sxy : 0.f);
                sb += (g > 180) ? s4 : ((g == 180) ? szw : 0.f);
            }
        }
        se[2 * p]     = sa;
        se[2 * p + 1] = sb;
    }

    // ---- butterfly-reduce each row's sum-of-exp across the wave ----
    #pragma unroll
    for (int rr = 0; rr < ROWS_PER_WAVE; ++rr) {
        #pragma unroll
        for (int off = 32; off > 0; off >>= 1)
            se[rr] += __shfl_xor(se[rr], off, 64);
    }

    // ---- tap phase: lane = 8*grr + gj -> row grr (0..7), tap gj (0..6) ----
    // Closed-form smoothed label: w(c) = DECAYS[|c-t|] (|c-t|<=3, 0<=c<NC),
    // center 1.0 — the overwrite-scatter's last writer is always smallest-dist.
    const int grr = lane >> 3;
    const int gj  = lane & 7;
    const float s01 = (grr & 1) ? se[1] : se[0];
    const float s23 = (grr & 1) ? se[3] : se[2];
    const float s45 = (grr & 1) ? se[5] : se[4];
    const float s67 = (grr & 1) ? se[7] : se[6];
    const float s0123 = (grr & 2) ? s23 : s01;
    const float s4567 = (grr & 2) ? s67 : s45;
    const float se_sel = (grr & 4) ? s4567 : s0123;
    const int u01 = (grr & 1) ? t1 : t0;
    const int u23 = (grr & 1) ? t3 : t2;
    const int u45 = (grr & 1) ? t5 : t4;
    const int u67 = (grr & 1) ? t7 : t6;
    const int u0123 = (grr & 2) ? u23 : u01;
    const int u4567 = (grr & 2) ? u67 : u45;
    const int t_sel = (grr & 4) ? u4567 : u0123;

    int ad = gj - 3; ad = (ad < 0) ? -ad : ad;      // |gj-3|
    const float w = (ad == 0) ? 1.0f
                  : (ad == 1) ? 0.606530659713f     // exp(-1/2)
                  : (ad == 2) ? 0.367879441171f     // exp(-1)
                  : (ad == 3) ? 0.135335283237f     // exp(-2)
                  : 0.0f;                           // gj==7 slot
    const int c = t_sel - 3 + gj;
    const bool tap_valid = (gj < 7) & (c >= 0) & (c <= NC - 1);
    int cc = c; if (cc < 0) cc = 0; if (cc > NC - 1) cc = NC - 1;
    const float pv = pred[(size_t)(row0 + grr) * NC + cc];  // cache-hot
    const float lse = __logf(se_sel);
    float contrib = tap_valid ? (w * (lse - pv)) : 0.f;

    #pragma unroll
    for (int off = 32; off > 0; off >>= 1)
        contrib += __shfl_xor(contrib, off, 64);

    if (lane == 0) wave_sums[wave] = contrib;
    __syncthreads();
    if (threadIdx.x == 0) {
        partials[blockIdx.x] =
            wave_sums[0] + wave_sums[1] + wave_sums[2] + wave_sums[3];
    }
}

__global__ __launch_bounds__(256) void reduce_partials_kernel(
        const float* __restrict__ partials, float* __restrict__ out) {
    const int lane = threadIdx.x & 63;
    const int wave = threadIdx.x >> 6;
    __shared__ float ws[4];

    float s = 0.f;
    #pragma unroll
    for (int k = 0; k < NBLOCKS / 256; ++k)          // 8 coalesced iters
        s += partials[threadIdx.x + (k << 8)];
    #pragma unroll
    for (int off = 32; off > 0; off >>= 1)
        s += __shfl_xor(s, off, 64);
    if (lane == 0) ws[wave] = s;
    __syncthreads();
    if (threadIdx.x == 0)
        out[0] = (ws[0] + ws[1] + ws[2] + ws[3]) * (1.0f / (float)NROWS);
}

extern "C" void kernel_launch(void* const* d_in, const int* in_sizes, int n_in,
                              void* d_out, int out_size, void* d_ws, size_t ws_size,
                              hipStream_t stream) {
    const float* pred = (const float*)d_in[0];
    const int* target = (const int*)d_in[1];
    float* out = (float*)d_out;
    float* partials = (float*)d_ws;   // 2048 floats = 8 KB

    ce_gauss_kernel<<<NBLOCKS, 256, 0, stream>>>(pred, target, partials);
    reduce_partials_kernel<<<1, 256, 0, stream>>>(partials, out);
}